// Round 12
// baseline (361.461 us; speedup 1.0000x reference)
//
#include <hip/hip_runtime.h>
#include <stdint.h>

typedef unsigned short u16;
typedef __attribute__((ext_vector_type(8))) short short8;
typedef __attribute__((ext_vector_type(4))) float f32x4;
typedef __attribute__((ext_vector_type(16))) float f32x16;

#define B_ 2
#define S_ 2048
#define E_ 2048
#define H_ 16
#define D_ 128
#define M_ 4096

__device__ __forceinline__ u16 f2bf(float f) {
  unsigned u = __float_as_uint(f);
  u = u + 0x7FFFu + ((u >> 16) & 1u);
  return (u16)(u >> 16);
}
__device__ __forceinline__ float bf2f(u16 h) {
  return __uint_as_float(((unsigned)h) << 16);
}

// async global->LDS, 16B per lane; LDS dest is wave-uniform base + lane*16
#define GLD16(gp, lp) __builtin_amdgcn_global_load_lds(                      \
    (__attribute__((address_space(1))) void*)(gp),                           \
    (__attribute__((address_space(3))) void*)(lp), 16, 0, 0)

// ---------------------------------------------------------------- cast f32->bf16
__global__ void cast_bf16(const float4* __restrict__ src, ushort4* __restrict__ dst, int n4) {
  int i = blockIdx.x * 256 + threadIdx.x;
  if (i < n4) {
    float4 v = src[i];
    ushort4 o;
    o.x = f2bf(v.x); o.y = f2bf(v.y); o.z = f2bf(v.z); o.w = f2bf(v.w);
    dst[i] = o;
  }
}

// 4 weight casts in one launch (blockIdx.y selects the tensor); o0..o2 contiguous -> [Wq;Wk;Wv]
__global__ void cast4_bf16(const float4* __restrict__ w0, const float4* __restrict__ w1,
                           const float4* __restrict__ w2, const float4* __restrict__ w3,
                           ushort4* __restrict__ o0, ushort4* __restrict__ o1,
                           ushort4* __restrict__ o2, ushort4* __restrict__ o3, int n4) {
  const int i = blockIdx.x * 256 + threadIdx.x;
  if (i >= n4) return;
  const float4* s; ushort4* d;
  switch (blockIdx.y) {
    case 0: s = w0; d = o0; break;
    case 1: s = w1; d = o1; break;
    case 2: s = w2; d = o2; break;
    default: s = w3; d = o3; break;
  }
  float4 v = s[i];
  ushort4 o;
  o.x = f2bf(v.x); o.y = f2bf(v.y); o.z = f2bf(v.z); o.w = f2bf(v.w);
  d[i] = o;
}

// ---------------------------------------------------------------- GEMM v4 (proven 123 us): phased,
// 2 barriers/tile, fused RoPE + V-transpose epilogue (MODE 0).
// C = A[M,K] @ W[N,K]^T.  BM=128, BN=256, BK=64. 8 waves, per-wave 64x64 output.
// 3-deep LDS ring. Per K-tile TWO phases:
//   {readA frags + stage0 -> BAR -> 16 MFMA} {readB frags + stage1 -> vmcnt(6) lgkmcnt(0) -> BAR -> 16 MFMA}
// vmcnt(6): at tile t's wait, own outstanding = tile t+2's 6 issues -> <=6 left certifies t+1 staged.
// T2: XOR(chunk,row&7) swizzle via inverse-permuted global source (conflicts measured 0).
// XCD swizzle: column bands (bxpx panels/XCD).  NOTE (round 11): B direct-to-reg REGRESSED
// (latency-chain, not LDS-throughput, is the binding constraint at 2 waves/SIMD) — keep B in LDS.
template <int MODE>
__launch_bounds__(512, 1)
__global__ void gemm256(const u16* __restrict__ A, const u16* __restrict__ Bw,
                        void* __restrict__ Cp, int M, int N, int K, int bxpx,
                        const float* __restrict__ cosT, const float* __restrict__ sinT) {
  __shared__ alignas(16) u16 SMEM[73728];   // 144 KB: LA 3x8192 u16 | LB 3x16384 u16
  u16* const LA = SMEM;
  u16* const LB = SMEM + 24576;
  const int tid = threadIdx.x, wave = tid >> 6, lane = tid & 63;
  const int xcd = blockIdx.x & 7;
  const int j = blockIdx.x >> 3;
  const int bx = xcd * bxpx + (j % bxpx);
  const int by = j / bxpx;
  const int m0 = by * 128, n0 = bx * 256;
  const int wm = (wave >> 2) * 64, wn = (wave & 3) * 64;
  const int lrow = lane & 15, lq = lane >> 4;

  auto stage0 = [&](int buf, int kt) {   // A tile (2 issues) + B issue 0
    const int k0 = kt * 64;
#pragma unroll
    for (int i = 0; i < 2; ++i) {
      const int c = i * 512 + tid;
      const int row = c >> 3, k = c & 7;
      GLD16(A + (size_t)(m0 + row) * K + k0 + ((k ^ (row & 7)) * 8),
            LA + buf * 8192 + i * 4096 + wave * 512);
    }
    {
      const int c = tid;
      const int row = c >> 3, k = c & 7;
      GLD16(Bw + (size_t)(n0 + row) * K + k0 + ((k ^ (row & 7)) * 8),
            LB + buf * 16384 + wave * 512);
    }
  };
  auto stage1 = [&](int buf, int kt) {   // B issues 1..3
    const int k0 = kt * 64;
#pragma unroll
    for (int i = 1; i < 4; ++i) {
      const int c = i * 512 + tid;
      const int row = c >> 3, k = c & 7;
      GLD16(Bw + (size_t)(n0 + row) * K + k0 + ((k ^ (row & 7)) * 8),
            LB + buf * 16384 + i * 4096 + wave * 512);
    }
  };

  f32x4 acc[4][4] = {};
  const int NT = K >> 6;                 // 32
  stage0(0, 0); stage1(0, 0);
  stage0(1, 1); stage1(1, 1);
  asm volatile("s_waitcnt vmcnt(6) lgkmcnt(0)" ::: "memory");  // tile 0 staged
  __builtin_amdgcn_sched_barrier(0);
  __builtin_amdgcn_s_barrier();

  for (int t = 0; t < NT; ++t) {
    const int cur = t % 3;
    const int sb = (t + 2) % 3;
    const bool dostage = (t + 2) < NT;

    // ===== phase A (k-chunk 0) =====
    short8 a0[4], b0[4];
#pragma unroll
    for (int m = 0; m < 4; ++m) {
      const int row = wm + m * 16 + lrow;
      a0[m] = *(const short8*)&LA[cur * 8192 + row * 64 + ((lq ^ (row & 7)) * 8)];
    }
#pragma unroll
    for (int n = 0; n < 4; ++n) {
      const int row = wn + n * 16 + lrow;
      b0[n] = *(const short8*)&LB[cur * 16384 + row * 64 + ((lq ^ (row & 7)) * 8)];
    }
    if (dostage) stage0(sb, t + 2);
    __builtin_amdgcn_sched_barrier(0);
    __builtin_amdgcn_s_barrier();
    __builtin_amdgcn_sched_barrier(0);
    __builtin_amdgcn_s_setprio(1);
#pragma unroll
    for (int m = 0; m < 4; ++m)
#pragma unroll
      for (int n = 0; n < 4; ++n)
        acc[m][n] = __builtin_amdgcn_mfma_f32_16x16x32_bf16(a0[m], b0[n], acc[m][n], 0, 0, 0);
    __builtin_amdgcn_s_setprio(0);

    // ===== phase B (k-chunk 1) =====
    short8 a1[4], b1[4];
#pragma unroll
    for (int m = 0; m < 4; ++m) {
      const int row = wm + m * 16 + lrow;
      a1[m] = *(const short8*)&LA[cur * 8192 + row * 64 + (((4 + lq) ^ (row & 7)) * 8)];
    }
#pragma unroll
    for (int n = 0; n < 4; ++n) {
      const int row = wn + n * 16 + lrow;
      b1[n] = *(const short8*)&LB[cur * 16384 + row * 64 + (((4 + lq) ^ (row & 7)) * 8)];
    }
    if (dostage) stage1(sb, t + 2);
    if (t < NT - 2) { asm volatile("s_waitcnt vmcnt(6) lgkmcnt(0)" ::: "memory"); }
    else            { asm volatile("s_waitcnt vmcnt(0) lgkmcnt(0)" ::: "memory"); }
    __builtin_amdgcn_sched_barrier(0);
    __builtin_amdgcn_s_barrier();
    __builtin_amdgcn_sched_barrier(0);
    __builtin_amdgcn_s_setprio(1);
#pragma unroll
    for (int m = 0; m < 4; ++m)
#pragma unroll
      for (int n = 0; n < 4; ++n)
        acc[m][n] = __builtin_amdgcn_mfma_f32_16x16x32_bf16(a1[m], b1[n], acc[m][n], 0, 0, 0);
    __builtin_amdgcn_s_setprio(0);
  }

  const int rbase = lq * 4;  // C/D: col = lane&15, row = (lane>>4)*4 + r
  if (MODE == 1) {
#pragma unroll
    for (int m = 0; m < 4; ++m)
#pragma unroll
      for (int n = 0; n < 4; ++n)
#pragma unroll
        for (int r = 0; r < 4; ++r) {
          const int mm = m0 + wm + m * 16 + rbase + r;
          const int nn = n0 + wn + n * 16 + lrow;
          ((float*)Cp)[(size_t)mm * N + nn] = acc[m][n][r];
        }
    return;
  }

  // ===== MODE 0 epilogue: C tile -> LDS -> fused rope / V-transpose =====
  u16* ct = SMEM;                        // [128][272] bf16
#pragma unroll
  for (int m = 0; m < 4; ++m)
#pragma unroll
    for (int n = 0; n < 4; ++n)
#pragma unroll
      for (int r = 0; r < 4; ++r)
        ct[(wm + m * 16 + rbase + r) * 272 + wn + n * 16 + lrow] = f2bf(acc[m][n][r]);
  __syncthreads();

  const int tz = n0 >> 11;               // 0=Q 1=K 2=V (block-uniform)
  const int bb = m0 >> 11, s0 = m0 & (S_ - 1);
  const int h0 = (n0 >> 7) & 15;
  const size_t NXc = (size_t)B_ * S_ * E_;
  u16* dst = (u16*)Cp + (size_t)tz * NXc;

  if (tz < 2) {
    const float sc = (tz == 0) ? 0.12751744154f : 1.f;  // Q pre-scale (1/sqrt(D))*log2(e)
#pragma unroll
    for (int i = 0; i < 8; ++i) {
      const int idx = i * 512 + tid;           // 4096 tasks = 128 rows x 32 col-chunks
      const int row = idx >> 5, c8 = (idx & 31) * 8;
      const int head = c8 >> 7, hd = c8 & 127;
      const int s = s0 + row;
      short8 self = *(const short8*)&ct[row * 272 + c8];
      short8 part = *(const short8*)&ct[row * 272 + (c8 ^ 64)];
      float4 cv0 = *(const float4*)&cosT[s * D_ + hd];
      float4 cv1 = *(const float4*)&cosT[s * D_ + hd + 4];
      float4 sv0 = *(const float4*)&sinT[s * D_ + hd];
      float4 sv1 = *(const float4*)&sinT[s * D_ + hd + 4];
      float cv[8] = {cv0.x, cv0.y, cv0.z, cv0.w, cv1.x, cv1.y, cv1.z, cv1.w};
      float sv[8] = {sv0.x, sv0.y, sv0.z, sv0.w, sv1.x, sv1.y, sv1.z, sv1.w};
      short8 o;
      if (hd < 64) {
#pragma unroll
        for (int jj = 0; jj < 8; ++jj) {
          const float x1 = bf2f((u16)self[jj]), x2 = bf2f((u16)part[jj]);
          o[jj] = (short)f2bf((x1 * cv[jj] - x2 * sv[jj]) * sc);
        }
      } else {
#pragma unroll
        for (int jj = 0; jj < 8; ++jj) {
          const float x2 = bf2f((u16)self[jj]), x1 = bf2f((u16)part[jj]);
          o[jj] = (short)f2bf((x2 * cv[jj] + x1 * sv[jj]) * sc);
        }
      }
      *(short8*)&dst[(((size_t)bb * H_ + h0 + head) * S_ + s) * D_ + hd] = o;
    }
  } else {
#pragma unroll
    for (int i = 0; i < 8; ++i) {
      const int task = i * 512 + tid;          // 4096 = 256 d-cols x 16 s-chunks
      const int dcol = task & 255, sch = task >> 8;
      short8 v;
#pragma unroll
      for (int jj = 0; jj < 8; ++jj) v[jj] = ct[(sch * 8 + jj) * 272 + dcol];
      const int h = h0 + (dcol >> 7), hd = dcol & 127;
      *(short8*)&dst[(((size_t)bb * H_ + h) * D_ + hd) * S_ + s0 + sch * 8] = v;
    }
  }
}

// ---------------------------------------------------------------- causal flash attention v6
// Round-5 16-wave structure, NO occupancy launch-bound (round-5 failure was the (1024,4)
// 64-VGPR cap -> spills; natural allocation is ~105-125 VGPR -> 16 waves/CU = 4 waves/SIMD).
// 16 waves (1024 thr), 4 KV-parity groups x 4 q-subwaves. KVBLK=32, double-buffered per group.
// Tiles per seg = 4t+4, divisible by 4 -> every group does exactly t+1 tiles. Pairing (15-p,p)
// -> uniform 17 iters per block. Merge: 2-round LDS tree, SB reused as O-buffer.
__launch_bounds__(1024)
__global__ void attn_fwd(const u16* __restrict__ Q, const u16* __restrict__ Kt,
                         const u16* __restrict__ VT, u16* __restrict__ Out) {
  __shared__ alignas(16) u16 SB[4][2][8192];   // [grp][buf][ K 32x128 | V^T 128x32 ]
  __shared__ float MLB[3][4][64][2];
  const int tid = threadIdx.x, wave = tid >> 6, lane = tid & 63;
  const int grp = wave >> 2, w4 = wave & 3;
  // bijective XCD swizzle (256 % 8 == 0): 4 heads per XCD
  const int hw = blockIdx.x;
  const int lid = (hw & 7) * 32 + (hw >> 3);
  const int p = lid & 7, bh = lid >> 3;
  const int bb = bh >> 4, h = bh & 15;
  const u16* Qh = Q + (size_t)bh * S_ * D_;
  const u16* Kh = Kt + (size_t)bh * S_ * D_;
  const u16* Vh = VT + (size_t)bh * D_ * S_;
  const int l31 = lane & 31, hi = lane >> 5;

  auto stage = [&](int buf, int kv0) {   // my group's 4 waves stage my stream (K 8KB + V 8KB)
#pragma unroll
    for (int pp = 0; pp < 2; ++pp) {
      const int g = pp * 4 + w4;       // 0..7 (wave-uniform)
      const int c = g * 64 + lane;     // 0..511
      const int srow = c >> 4, dch = c & 15;
      GLD16(Kh + (size_t)(kv0 + srow) * D_ + ((dch ^ (srow & 7)) * 8), &SB[grp][buf][g * 512]);
      const int drow = c >> 2, sch = c & 3;
      GLD16(Vh + (size_t)drow * S_ + kv0 + ((sch ^ (drow & 3)) * 8), &SB[grp][buf][4096 + g * 512]);
    }
  };

  float* obufA = (float*)&SB[0][0][0];   // 64 KB (streams 0,1) - merge region A
  float* obufB = obufA + 16384;          // 64 KB (streams 2,3) - merge region B

  const int qts[2] = {15 - p, p};
#pragma unroll 1
  for (int seg = 0; seg < 2; ++seg) {
    const int t = qts[seg];
    const int iters = t + 1;             // my group's KV32 tiles: tix = i*4 + grp
    const int q0 = t * 128 + w4 * 32;
    const int qg = q0 + l31;

    // Q fragments (B-operand): lane holds Q[qg][m*16 + hi*8 + j], j=0..7
    short8 qf[8];
#pragma unroll
    for (int m = 0; m < 8; ++m)
      qf[m] = *(const short8*)&Qh[(size_t)qg * D_ + m * 16 + hi * 8];

    f32x16 od[4] = {};   // out^T: od[dt], d = dt*32 + (reg&3)+8*(reg>>2)+4*hi, col q = l31
    float mr = 0.f, lsum = 0.f;          // mr init 0: masked tiles give exp2(-1e30) = 0

    stage(0, grp * 32);
    int cur = 0;

    for (int i = 0; i < iters; ++i) {
      __syncthreads();  // all streams' buf[cur] staged; prior reads of buf[cur^1] done
      if (i + 1 < iters) stage(cur ^ 1, ((i + 1) * 4 + grp) * 32);
      const int kv0 = (i * 4 + grp) * 32;
      const u16* Kc = &SB[grp][cur][0];
      const u16* Vc = &SB[grp][cur][4096];

      // QK^T swapped: S^T[k][q] for 32 kv rows
      f32x16 s0 = {};
      __builtin_amdgcn_s_setprio(1);
#pragma unroll
      for (int m = 0; m < 8; ++m) {
        const int col = m * 16 + hi * 8;
        short8 k0 = *(const short8*)&Kc[l31 * 128 + (col ^ ((l31 & 7) << 3))];
        s0 = __builtin_amdgcn_mfma_f32_32x32x16_bf16(k0, qf[m], s0, 0, 0, 0);
      }
      __builtin_amdgcn_s_setprio(0);

      // causal mask
      if (kv0 + 31 > q0) {
#pragma unroll
        for (int r = 0; r < 16; ++r) {
          const int kg = kv0 + (r & 3) + 8 * (r >> 2) + 4 * hi;
          if (kg > qg) s0[r] = -1e30f;
        }
      }

      // online softmax (scores in log2 units via pre-scaled Q)
      float m0 = fmaxf(s0[0], s0[1]), m1 = fmaxf(s0[2], s0[3]);
      float m2 = fmaxf(s0[4], s0[5]), m3 = fmaxf(s0[6], s0[7]);
      float m4 = fmaxf(s0[8], s0[9]), m5 = fmaxf(s0[10], s0[11]);
      float m6 = fmaxf(s0[12], s0[13]), m7 = fmaxf(s0[14], s0[15]);
      float mloc = fmaxf(fmaxf(fmaxf(m0, m1), fmaxf(m2, m3)),
                         fmaxf(fmaxf(m4, m5), fmaxf(m6, m7)));
      const float mx = fmaxf(mloc, __shfl_xor(mloc, 32));
      const bool need = !__all(mx <= mr + 8.f);   // defer-max (T13)
      float corr = 1.f;
      if (need) {
        const float mnew = fmaxf(mr, mx);
        corr = exp2f(mr - mnew);
        mr = mnew;
      }
      float sloc = 0.f;
#pragma unroll
      for (int r = 0; r < 16; ++r) { s0[r] = exp2f(s0[r] - mr); sloc += s0[r]; }
      const float rsum = sloc + __shfl_xor(sloc, 32);
      lsum = lsum * corr + rsum;
      if (need) {
#pragma unroll
        for (int dt = 0; dt < 4; ++dt)
#pragma unroll
          for (int r = 0; r < 16; ++r) od[dt][r] *= corr;
      }

      // pack P to bf16 words: W0[c][pr] covers k32 = 8c + 4hi + {2pr, 2pr+1}
      unsigned W0[4][2];
#pragma unroll
      for (int c = 0; c < 4; ++c)
#pragma unroll
        for (int pr = 0; pr < 2; ++pr)
          asm("v_cvt_pk_bf16_f32 %0, %1, %2"
              : "=v"(W0[c][pr]) : "v"(s0[4 * c + 2 * pr]), "v"(s0[4 * c + 2 * pr + 1]));

      // PV: out^T += V^T * P^T ; B-frag for group kk needs k = kk*16 + hi*8 + j
      __builtin_amdgcn_s_setprio(1);
#pragma unroll
      for (int kk = 0; kk < 2; ++kk) {
        const int cown = 2 * kk + hi, csend = 2 * kk + 1 - hi;
        const unsigned o0 = W0[cown][0], o1 = W0[cown][1];
        const unsigned r0 = (unsigned)__shfl_xor((int)W0[csend][0], 32);
        const unsigned r1 = (unsigned)__shfl_xor((int)W0[csend][1], 32);
        uint4 bw;
        if (hi == 0) bw = make_uint4(o0, o1, r0, r1);
        else         bw = make_uint4(r0, r1, o0, o1);
        const short8 pf = *(const short8*)&bw;
        const int slot = 2 * kk + hi;    // V chunk col for this k-16 group
#pragma unroll
        for (int dt = 0; dt < 4; ++dt) {
          const int row = dt * 32 + l31;
          const short8 vf = *(const short8*)&Vc[row * 32 + ((slot ^ (row & 3)) * 8)];
          od[dt] = __builtin_amdgcn_mfma_f32_32x32x16_bf16(vf, pf, od[dt], 0, 0, 0);
        }
      }
      __builtin_amdgcn_s_setprio(0);
      cur ^= 1;
    }

    // ---- 2-round merge tree: (1->0), (3->2), then (2->0) ----
    __syncthreads();                      // all compute done; SB reusable as O-buffer
    if (grp == 1 || grp == 3) {
      float* ob = (grp == 1) ? obufA : obufB;
      MLB[grp - 1][w4][lane][0] = mr;
      MLB[grp - 1][w4][lane][1] = lsum;
#pragma unroll
      for (int dt = 0; dt < 4; ++dt)
#pragma unroll
        for (int r = 0; r < 16; ++r)
          ob[(dt * 16 + r) * 256 + w4 * 64 + lane] = od[dt][r];   // lane-major: conflict-free
    }
    __syncthreads();
    if (grp == 0 || grp == 2) {
      const float* ob = (grp == 0) ? obufA : obufB;
      const float mB = MLB[grp][w4][lane][0];     // grp0 reads slot0 (grp1), grp2 slot2 (grp3)
      const float lB = MLB[grp][w4][lane][1];
      const float m = fmaxf(mr, mB);
      const float aA = exp2f(mr - m), aB = exp2f(mB - m);
      lsum = lsum * aA + lB * aB;
      mr = m;
#pragma unroll
      for (int dt = 0; dt < 4; ++dt)
#pragma unroll
        for (int r = 0; r < 16; ++r)
          od[dt][r] = od[dt][r] * aA + ob[(dt * 16 + r) * 256 + w4 * 64 + lane] * aB;
    }
    __syncthreads();
    if (grp == 2) {
      MLB[1][w4][lane][0] = mr;
      MLB[1][w4][lane][1] = lsum;
#pragma unroll
      for (int dt = 0; dt < 4; ++dt)
#pragma unroll
        for (int r = 0; r < 16; ++r)
          obufA[(dt * 16 + r) * 256 + w4 * 64 + lane] = od[dt][r];
    }
    __syncthreads();
    if (grp == 0) {
      const float mB = MLB[1][w4][lane][0];
      const float lB = MLB[1][w4][lane][1];
      const float m = fmaxf(mr, mB);
      const float aA = exp2f(mr - m), aB = exp2f(mB - m);
      lsum = lsum * aA + lB * aB;
#pragma unroll
      for (int dt = 0; dt < 4; ++dt)
#pragma unroll
        for (int r = 0; r < 16; ++r)
          od[dt][r] = od[dt][r] * aA + obufA[(dt * 16 + r) * 256 + w4 * 64 + lane] * aB;

      // finalize: o /= l, write bf16 to attn buffer laid out [B,S,E]
      const float inv = 1.f / lsum;
      const size_t obase = ((size_t)bb * S_ + qg) * E_ + h * D_;
#pragma unroll
      for (int dt = 0; dt < 4; ++dt)
#pragma unroll
        for (int g = 0; g < 4; ++g) {
          ushort4 w;
          w.x = f2bf(od[dt][4 * g + 0] * inv);
          w.y = f2bf(od[dt][4 * g + 1] * inv);
          w.z = f2bf(od[dt][4 * g + 2] * inv);
          w.w = f2bf(od[dt][4 * g + 3] * inv);
          *(ushort4*)&Out[obase + dt * 32 + 8 * g + 4 * hi] = w;
        }
    }
    __syncthreads();                      // merge reads done before next seg restages SB
  }
}

// ---------------------------------------------------------------- launcher
extern "C" void kernel_launch(void* const* d_in, const int* in_sizes, int n_in,
                              void* d_out, int out_size, void* d_ws, size_t ws_size,
                              hipStream_t stream) {
  const float* x    = (const float*)d_in[0];
  const float* cosT = (const float*)d_in[1];
  const float* sinT = (const float*)d_in[2];
  const float* Wq   = (const float*)d_in[3];
  const float* Wk   = (const float*)d_in[4];
  const float* Wv   = (const float*)d_in[5];
  const float* Wo   = (const float*)d_in[6];
  float* out = (float*)d_out;

  const size_t NX = (size_t)B_ * S_ * E_;  // 8388608
  const size_t NW = (size_t)E_ * E_;       // 4194304
  u16* ws  = (u16*)d_ws;
  u16* xb  = ws;
  u16* Wqb = xb + NX;        // [Wq;Wk;Wv] contiguous -> fused [6144][2048]
  u16* Wkb = Wqb + NW;
  u16* Wvb = Wkb + NW;
  u16* Wob = Wvb + NW;
  u16* Qb  = Wob + NW;       // Qb, Kb, VTb contiguous (gemm MODE 0 writes tz*NX offsets)
  u16* Kb  = Qb + NX;
  u16* VTb = Kb + NX;        // V written pre-transposed [B,H,D,S] by the epilogue
  u16* Ab  = VTb + NX;

  cast_bf16<<<(int)(NX / 4 / 256), 256, 0, stream>>>((const float4*)x, (ushort4*)xb, (int)(NX / 4));
  cast4_bf16<<<dim3((int)(NW / 4 / 256), 4), 256, 0, stream>>>(
      (const float4*)Wq, (const float4*)Wk, (const float4*)Wv, (const float4*)Wo,
      (ushort4*)Wqb, (ushort4*)Wkb, (ushort4*)Wvb, (ushort4*)Wob, (int)(NW / 4));

  // fused QKV projection + rope(Q,K) + V-transpose, all in one dispatch
  gemm256<0><<<dim3(768), 512, 0, stream>>>(xb, Wqb, Qb, M_, 3 * E_, E_, 3, cosT, sinT);

  attn_fwd<<<dim3(256), 1024, 0, stream>>>(Qb, Kb, VTb, Ab);

  gemm256<1><<<dim3(256), 512, 0, stream>>>(Ab, Wob, out, M_, E_, E_, 1, nullptr, nullptr);
}

// Round 13
// 337.858 us; speedup vs baseline: 1.0699x; 1.0699x over previous
//
#include <hip/hip_runtime.h>
#include <stdint.h>

typedef unsigned short u16;
typedef __attribute__((ext_vector_type(8))) short short8;
typedef __attribute__((ext_vector_type(4))) float f32x4;
typedef __attribute__((ext_vector_type(16))) float f32x16;

#define B_ 2
#define S_ 2048
#define E_ 2048
#define H_ 16
#define D_ 128
#define M_ 4096

__device__ __forceinline__ u16 f2bf(float f) {
  unsigned u = __float_as_uint(f);
  u = u + 0x7FFFu + ((u >> 16) & 1u);
  return (u16)(u >> 16);
}
__device__ __forceinline__ float bf2f(u16 h) {
  return __uint_as_float(((unsigned)h) << 16);
}

// async global->LDS, 16B per lane; LDS dest is wave-uniform base + lane*16
#define GLD16(gp, lp) __builtin_amdgcn_global_load_lds(                      \
    (__attribute__((address_space(1))) void*)(gp),                           \
    (__attribute__((address_space(3))) void*)(lp), 16, 0, 0)

// ---------------------------------------------------------------- cast f32->bf16
__global__ void cast_bf16(const float4* __restrict__ src, ushort4* __restrict__ dst, int n4) {
  int i = blockIdx.x * 256 + threadIdx.x;
  if (i < n4) {
    float4 v = src[i];
    ushort4 o;
    o.x = f2bf(v.x); o.y = f2bf(v.y); o.z = f2bf(v.z); o.w = f2bf(v.w);
    dst[i] = o;
  }
}

// 4 weight casts in one launch (blockIdx.y selects the tensor); o0..o2 contiguous -> [Wq;Wk;Wv]
__global__ void cast4_bf16(const float4* __restrict__ w0, const float4* __restrict__ w1,
                           const float4* __restrict__ w2, const float4* __restrict__ w3,
                           ushort4* __restrict__ o0, ushort4* __restrict__ o1,
                           ushort4* __restrict__ o2, ushort4* __restrict__ o3, int n4) {
  const int i = blockIdx.x * 256 + threadIdx.x;
  if (i >= n4) return;
  const float4* s; ushort4* d;
  switch (blockIdx.y) {
    case 0: s = w0; d = o0; break;
    case 1: s = w1; d = o1; break;
    case 2: s = w2; d = o2; break;
    default: s = w3; d = o3; break;
  }
  float4 v = s[i];
  ushort4 o;
  o.x = f2bf(v.x); o.y = f2bf(v.y); o.z = f2bf(v.z); o.w = f2bf(v.w);
  d[i] = o;
}

// ---------------------------------------------------------------- GEMM v4 (proven 123 us): phased,
// 2 barriers/tile, fused RoPE + V-transpose epilogue (MODE 0).  Unchanged from round 10.
template <int MODE>
__launch_bounds__(512, 1)
__global__ void gemm256(const u16* __restrict__ A, const u16* __restrict__ Bw,
                        void* __restrict__ Cp, int M, int N, int K, int bxpx,
                        const float* __restrict__ cosT, const float* __restrict__ sinT) {
  __shared__ alignas(16) u16 SMEM[73728];   // 144 KB: LA 3x8192 u16 | LB 3x16384 u16
  u16* const LA = SMEM;
  u16* const LB = SMEM + 24576;
  const int tid = threadIdx.x, wave = tid >> 6, lane = tid & 63;
  const int xcd = blockIdx.x & 7;
  const int j = blockIdx.x >> 3;
  const int bx = xcd * bxpx + (j % bxpx);
  const int by = j / bxpx;
  const int m0 = by * 128, n0 = bx * 256;
  const int wm = (wave >> 2) * 64, wn = (wave & 3) * 64;
  const int lrow = lane & 15, lq = lane >> 4;

  auto stage0 = [&](int buf, int kt) {   // A tile (2 issues) + B issue 0
    const int k0 = kt * 64;
#pragma unroll
    for (int i = 0; i < 2; ++i) {
      const int c = i * 512 + tid;
      const int row = c >> 3, k = c & 7;
      GLD16(A + (size_t)(m0 + row) * K + k0 + ((k ^ (row & 7)) * 8),
            LA + buf * 8192 + i * 4096 + wave * 512);
    }
    {
      const int c = tid;
      const int row = c >> 3, k = c & 7;
      GLD16(Bw + (size_t)(n0 + row) * K + k0 + ((k ^ (row & 7)) * 8),
            LB + buf * 16384 + wave * 512);
    }
  };
  auto stage1 = [&](int buf, int kt) {   // B issues 1..3
    const int k0 = kt * 64;
#pragma unroll
    for (int i = 1; i < 4; ++i) {
      const int c = i * 512 + tid;
      const int row = c >> 3, k = c & 7;
      GLD16(Bw + (size_t)(n0 + row) * K + k0 + ((k ^ (row & 7)) * 8),
            LB + buf * 16384 + i * 4096 + wave * 512);
    }
  };

  f32x4 acc[4][4] = {};
  const int NT = K >> 6;                 // 32
  stage0(0, 0); stage1(0, 0);
  stage0(1, 1); stage1(1, 1);
  asm volatile("s_waitcnt vmcnt(6) lgkmcnt(0)" ::: "memory");  // tile 0 staged
  __builtin_amdgcn_sched_barrier(0);
  __builtin_amdgcn_s_barrier();

  for (int t = 0; t < NT; ++t) {
    const int cur = t % 3;
    const int sb = (t + 2) % 3;
    const bool dostage = (t + 2) < NT;

    // ===== phase A (k-chunk 0) =====
    short8 a0[4], b0[4];
#pragma unroll
    for (int m = 0; m < 4; ++m) {
      const int row = wm + m * 16 + lrow;
      a0[m] = *(const short8*)&LA[cur * 8192 + row * 64 + ((lq ^ (row & 7)) * 8)];
    }
#pragma unroll
    for (int n = 0; n < 4; ++n) {
      const int row = wn + n * 16 + lrow;
      b0[n] = *(const short8*)&LB[cur * 16384 + row * 64 + ((lq ^ (row & 7)) * 8)];
    }
    if (dostage) stage0(sb, t + 2);
    __builtin_amdgcn_sched_barrier(0);
    __builtin_amdgcn_s_barrier();
    __builtin_amdgcn_sched_barrier(0);
    __builtin_amdgcn_s_setprio(1);
#pragma unroll
    for (int m = 0; m < 4; ++m)
#pragma unroll
      for (int n = 0; n < 4; ++n)
        acc[m][n] = __builtin_amdgcn_mfma_f32_16x16x32_bf16(a0[m], b0[n], acc[m][n], 0, 0, 0);
    __builtin_amdgcn_s_setprio(0);

    // ===== phase B (k-chunk 1) =====
    short8 a1[4], b1[4];
#pragma unroll
    for (int m = 0; m < 4; ++m) {
      const int row = wm + m * 16 + lrow;
      a1[m] = *(const short8*)&LA[cur * 8192 + row * 64 + (((4 + lq) ^ (row & 7)) * 8)];
    }
#pragma unroll
    for (int n = 0; n < 4; ++n) {
      const int row = wn + n * 16 + lrow;
      b1[n] = *(const short8*)&LB[cur * 16384 + row * 64 + (((4 + lq) ^ (row & 7)) * 8)];
    }
    if (dostage) stage1(sb, t + 2);
    if (t < NT - 2) { asm volatile("s_waitcnt vmcnt(6) lgkmcnt(0)" ::: "memory"); }
    else            { asm volatile("s_waitcnt vmcnt(0) lgkmcnt(0)" ::: "memory"); }
    __builtin_amdgcn_sched_barrier(0);
    __builtin_amdgcn_s_barrier();
    __builtin_amdgcn_sched_barrier(0);
    __builtin_amdgcn_s_setprio(1);
#pragma unroll
    for (int m = 0; m < 4; ++m)
#pragma unroll
      for (int n = 0; n < 4; ++n)
        acc[m][n] = __builtin_amdgcn_mfma_f32_16x16x32_bf16(a1[m], b1[n], acc[m][n], 0, 0, 0);
    __builtin_amdgcn_s_setprio(0);
  }

  const int rbase = lq * 4;  // C/D: col = lane&15, row = (lane>>4)*4 + r
  if (MODE == 1) {
#pragma unroll
    for (int m = 0; m < 4; ++m)
#pragma unroll
      for (int n = 0; n < 4; ++n)
#pragma unroll
        for (int r = 0; r < 4; ++r) {
          const int mm = m0 + wm + m * 16 + rbase + r;
          const int nn = n0 + wn + n * 16 + lrow;
          ((float*)Cp)[(size_t)mm * N + nn] = acc[m][n][r];
        }
    return;
  }

  // ===== MODE 0 epilogue: C tile -> LDS -> fused rope / V-transpose =====
  u16* ct = SMEM;                        // [128][272] bf16
#pragma unroll
  for (int m = 0; m < 4; ++m)
#pragma unroll
    for (int n = 0; n < 4; ++n)
#pragma unroll
      for (int r = 0; r < 4; ++r)
        ct[(wm + m * 16 + rbase + r) * 272 + wn + n * 16 + lrow] = f2bf(acc[m][n][r]);
  __syncthreads();

  const int tz = n0 >> 11;               // 0=Q 1=K 2=V (block-uniform)
  const int bb = m0 >> 11, s0 = m0 & (S_ - 1);
  const int h0 = (n0 >> 7) & 15;
  const size_t NXc = (size_t)B_ * S_ * E_;
  u16* dst = (u16*)Cp + (size_t)tz * NXc;

  if (tz < 2) {
    const float sc = (tz == 0) ? 0.12751744154f : 1.f;  // Q pre-scale (1/sqrt(D))*log2(e)
#pragma unroll
    for (int i = 0; i < 8; ++i) {
      const int idx = i * 512 + tid;           // 4096 tasks = 128 rows x 32 col-chunks
      const int row = idx >> 5, c8 = (idx & 31) * 8;
      const int head = c8 >> 7, hd = c8 & 127;
      const int s = s0 + row;
      short8 self = *(const short8*)&ct[row * 272 + c8];
      short8 part = *(const short8*)&ct[row * 272 + (c8 ^ 64)];
      float4 cv0 = *(const float4*)&cosT[s * D_ + hd];
      float4 cv1 = *(const float4*)&cosT[s * D_ + hd + 4];
      float4 sv0 = *(const float4*)&sinT[s * D_ + hd];
      float4 sv1 = *(const float4*)&sinT[s * D_ + hd + 4];
      float cv[8] = {cv0.x, cv0.y, cv0.z, cv0.w, cv1.x, cv1.y, cv1.z, cv1.w};
      float sv[8] = {sv0.x, sv0.y, sv0.z, sv0.w, sv1.x, sv1.y, sv1.z, sv1.w};
      short8 o;
      if (hd < 64) {
#pragma unroll
        for (int jj = 0; jj < 8; ++jj) {
          const float x1 = bf2f((u16)self[jj]), x2 = bf2f((u16)part[jj]);
          o[jj] = (short)f2bf((x1 * cv[jj] - x2 * sv[jj]) * sc);
        }
      } else {
#pragma unroll
        for (int jj = 0; jj < 8; ++jj) {
          const float x2 = bf2f((u16)self[jj]), x1 = bf2f((u16)part[jj]);
          o[jj] = (short)f2bf((x2 * cv[jj] + x1 * sv[jj]) * sc);
        }
      }
      *(short8*)&dst[(((size_t)bb * H_ + h0 + head) * S_ + s) * D_ + hd] = o;
    }
  } else {
#pragma unroll
    for (int i = 0; i < 8; ++i) {
      const int task = i * 512 + tid;          // 4096 = 256 d-cols x 16 s-chunks
      const int dcol = task & 255, sch = task >> 8;
      short8 v;
#pragma unroll
      for (int jj = 0; jj < 8; ++jj) v[jj] = ct[(sch * 8 + jj) * 272 + dcol];
      const int h = h0 + (dcol >> 7), hd = dcol & 127;
      *(short8*)&dst[(((size_t)bb * H_ + h) * D_ + hd) * S_ + s0 + sch * 8] = v;
    }
  }
}

// ---------------------------------------------------------------- causal flash attention v8
// 512 blocks x 512 threads, 2 blocks/CU (LDS 66 KB, VGPR capped 128 via (512,4)).
// Block = ONE 128-row q-tile (4 q-waves x 32q), 2 KV-parity groups (waves 0-3 even KV32
// tiles, 4-7 odd), KVBLK=32 double-buffered per group. iters = 2qt+2 per group (uniform
// within block). Cross-block causal balance via dispatch-order pairing: per XCD, slot s
// (qt = s&15) and slot s+32 (qt = 15-(s&15)) land on the same CU under round-robin ->
// each CU sums to 34 KV32-units. Round-12 lesson: 1024-thr blocks get VGPR capped at 64
// (spill disaster) -> 16 waves/CU must come from 2x512-thr blocks.
__launch_bounds__(512, 4)
__global__ void attn_fwd(const u16* __restrict__ Q, const u16* __restrict__ Kt,
                         const u16* __restrict__ VT, u16* __restrict__ Out) {
  __shared__ alignas(16) u16 SB[2][2][8192];   // [grp][buf][ K 32x128 | V^T 128x32 ] = 64 KB
  __shared__ float MLB[4][64][2];
  const int tid = threadIdx.x, wave = tid >> 6, lane = tid & 63;
  const int grp = wave >> 2, w4 = wave & 3;
  // block mapping: xcd-major, complementary qt halves for co-resident balance
  const int hw = blockIdx.x;
  const int xcd = hw & 7, slot = hw >> 3;       // slot 0..63
  const int half = slot >> 5, s5 = slot & 31;
  const int bh = xcd * 4 + (s5 >> 4) + 2 * half;   // 4 heads per XCD (L2 locality)
  const int qt = half ? 15 - (s5 & 15) : (s5 & 15);
  const int bb = bh >> 4, h = bh & 15;
  const u16* Qh = Q + (size_t)bh * S_ * D_;
  const u16* Kh = Kt + (size_t)bh * S_ * D_;
  const u16* Vh = VT + (size_t)bh * D_ * S_;
  const int l31 = lane & 31, hi = lane >> 5;

  auto stage = [&](int buf, int kv0) {   // my group's 4 waves stage my stream (K 8KB + V 8KB)
#pragma unroll
    for (int pp = 0; pp < 2; ++pp) {
      const int g = pp * 4 + w4;       // 0..7 (wave-uniform)
      const int c = g * 64 + lane;     // 0..511
      const int srow = c >> 4, dch = c & 15;
      GLD16(Kh + (size_t)(kv0 + srow) * D_ + ((dch ^ (srow & 7)) * 8), &SB[grp][buf][g * 512]);
      const int drow = c >> 2, sch = c & 3;
      GLD16(Vh + (size_t)drow * S_ + kv0 + ((sch ^ (drow & 3)) * 8), &SB[grp][buf][4096 + g * 512]);
    }
  };

  float* obuf = (float*)&SB[0][0][0];    // merge region: all 64 KB of SB (16384 floats)

  const int iters = 2 * qt + 2;          // my group's KV32 tiles: tix = 2i + grp
  const int q0 = qt * 128 + w4 * 32;
  const int qg = q0 + l31;

  // Q fragments (B-operand): lane holds Q[qg][m*16 + hi*8 + j], j=0..7
  short8 qf[8];
#pragma unroll
  for (int m = 0; m < 8; ++m)
    qf[m] = *(const short8*)&Qh[(size_t)qg * D_ + m * 16 + hi * 8];

  f32x16 od[4] = {};   // out^T: od[dt], d = dt*32 + (reg&3)+8*(reg>>2)+4*hi, col q = l31
  float mr = 0.f, lsum = 0.f;            // mr init 0: masked tiles give exp2(-1e30) = 0

  stage(0, grp * 32);
  int cur = 0;

  for (int i = 0; i < iters; ++i) {
    __syncthreads();  // both streams' buf[cur] staged; prior reads of buf[cur^1] done
    if (i + 1 < iters) stage(cur ^ 1, (2 * (i + 1) + grp) * 32);
    const int kv0 = (2 * i + grp) * 32;
    const u16* Kc = &SB[grp][cur][0];
    const u16* Vc = &SB[grp][cur][4096];

    // QK^T swapped: S^T[k][q] for 32 kv rows
    f32x16 s0 = {};
    __builtin_amdgcn_s_setprio(1);
#pragma unroll
    for (int m = 0; m < 8; ++m) {
      const int col = m * 16 + hi * 8;
      short8 k0 = *(const short8*)&Kc[l31 * 128 + (col ^ ((l31 & 7) << 3))];
      s0 = __builtin_amdgcn_mfma_f32_32x32x16_bf16(k0, qf[m], s0, 0, 0, 0);
    }
    __builtin_amdgcn_s_setprio(0);

    // causal mask
    if (kv0 + 31 > q0) {
#pragma unroll
      for (int r = 0; r < 16; ++r) {
        const int kg = kv0 + (r & 3) + 8 * (r >> 2) + 4 * hi;
        if (kg > qg) s0[r] = -1e30f;
      }
    }

    // online softmax (scores in log2 units via pre-scaled Q)
    float m0 = fmaxf(s0[0], s0[1]), m1 = fmaxf(s0[2], s0[3]);
    float m2 = fmaxf(s0[4], s0[5]), m3 = fmaxf(s0[6], s0[7]);
    float m4 = fmaxf(s0[8], s0[9]), m5 = fmaxf(s0[10], s0[11]);
    float m6 = fmaxf(s0[12], s0[13]), m7 = fmaxf(s0[14], s0[15]);
    float mloc = fmaxf(fmaxf(fmaxf(m0, m1), fmaxf(m2, m3)),
                       fmaxf(fmaxf(m4, m5), fmaxf(m6, m7)));
    const float mx = fmaxf(mloc, __shfl_xor(mloc, 32));
    const bool need = !__all(mx <= mr + 8.f);   // defer-max (T13)
    float corr = 1.f;
    if (need) {
      const float mnew = fmaxf(mr, mx);
      corr = exp2f(mr - mnew);
      mr = mnew;
    }
    float sloc = 0.f;
#pragma unroll
    for (int r = 0; r < 16; ++r) { s0[r] = exp2f(s0[r] - mr); sloc += s0[r]; }
    const float rsum = sloc + __shfl_xor(sloc, 32);
    lsum = lsum * corr + rsum;
    if (need) {
#pragma unroll
      for (int dt = 0; dt < 4; ++dt)
#pragma unroll
        for (int r = 0; r < 16; ++r) od[dt][r] *= corr;
    }

    // pack P to bf16 words: W0[c][pr] covers k32 = 8c + 4hi + {2pr, 2pr+1}
    unsigned W0[4][2];
#pragma unroll
    for (int c = 0; c < 4; ++c)
#pragma unroll
      for (int pr = 0; pr < 2; ++pr)
        asm("v_cvt_pk_bf16_f32 %0, %1, %2"
            : "=v"(W0[c][pr]) : "v"(s0[4 * c + 2 * pr]), "v"(s0[4 * c + 2 * pr + 1]));

    // PV: out^T += V^T * P^T ; B-frag for group kk needs k = kk*16 + hi*8 + j
    __builtin_amdgcn_s_setprio(1);
#pragma unroll
    for (int kk = 0; kk < 2; ++kk) {
      const int cown = 2 * kk + hi, csend = 2 * kk + 1 - hi;
      const unsigned o0 = W0[cown][0], o1 = W0[cown][1];
      const unsigned r0 = (unsigned)__shfl_xor((int)W0[csend][0], 32);
      const unsigned r1 = (unsigned)__shfl_xor((int)W0[csend][1], 32);
      uint4 bw;
      if (hi == 0) bw = make_uint4(o0, o1, r0, r1);
      else         bw = make_uint4(r0, r1, o0, o1);
      const short8 pf = *(const short8*)&bw;
      const int slotv = 2 * kk + hi;     // V chunk col for this k-16 group
#pragma unroll
      for (int dt = 0; dt < 4; ++dt) {
        const int row = dt * 32 + l31;
        const short8 vf = *(const short8*)&Vc[row * 32 + ((slotv ^ (row & 3)) * 8)];
        od[dt] = __builtin_amdgcn_mfma_f32_32x32x16_bf16(vf, pf, od[dt], 0, 0, 0);
      }
    }
    __builtin_amdgcn_s_setprio(0);
    cur ^= 1;
  }

  // ---- merge the two parity partials (group B -> LDS -> group A combines) ----
  __syncthreads();                     // all computes done; SB reusable as O-buffer
  if (grp == 1) {
    MLB[w4][lane][0] = mr;
    MLB[w4][lane][1] = lsum;
#pragma unroll
    for (int dt = 0; dt < 4; ++dt)
#pragma unroll
      for (int r = 0; r < 16; ++r)
        obuf[(dt * 16 + r) * 256 + w4 * 64 + lane] = od[dt][r];  // lane-major: conflict-free
  }
  __syncthreads();
  if (grp == 0) {
    const float mB = MLB[w4][lane][0];
    const float lB = MLB[w4][lane][1];
    const float m = fmaxf(mr, mB);
    const float aA = exp2f(mr - m), aB = exp2f(mB - m);
    lsum = lsum * aA + lB * aB;
#pragma unroll
    for (int dt = 0; dt < 4; ++dt)
#pragma unroll
      for (int r = 0; r < 16; ++r)
        od[dt][r] = od[dt][r] * aA + obuf[(dt * 16 + r) * 256 + w4 * 64 + lane] * aB;

    // finalize: o /= l, write bf16 to attn buffer laid out [B,S,E]
    const float inv = 1.f / lsum;
    const size_t obase = ((size_t)bb * S_ + qg) * E_ + h * D_;
#pragma unroll
    for (int dt = 0; dt < 4; ++dt)
#pragma unroll
      for (int g = 0; g < 4; ++g) {
        ushort4 w;
        w.x = f2bf(od[dt][4 * g + 0] * inv);
        w.y = f2bf(od[dt][4 * g + 1] * inv);
        w.z = f2bf(od[dt][4 * g + 2] * inv);
        w.w = f2bf(od[dt][4 * g + 3] * inv);
        *(ushort4*)&Out[obase + dt * 32 + 8 * g + 4 * hi] = w;
      }
  }
}

// ---------------------------------------------------------------- launcher
extern "C" void kernel_launch(void* const* d_in, const int* in_sizes, int n_in,
                              void* d_out, int out_size, void* d_ws, size_t ws_size,
                              hipStream_t stream) {
  const float* x    = (const float*)d_in[0];
  const float* cosT = (const float*)d_in[1];
  const float* sinT = (const float*)d_in[2];
  const float* Wq   = (const float*)d_in[3];
  const float* Wk   = (const float*)d_in[4];
  const float* Wv   = (const float*)d_in[5];
  const float* Wo   = (const float*)d_in[6];
  float* out = (float*)d_out;

  const size_t NX = (size_t)B_ * S_ * E_;  // 8388608
  const size_t NW = (size_t)E_ * E_;       // 4194304
  u16* ws  = (u16*)d_ws;
  u16* xb  = ws;
  u16* Wqb = xb + NX;        // [Wq;Wk;Wv] contiguous -> fused [6144][2048]
  u16* Wkb = Wqb + NW;
  u16* Wvb = Wkb + NW;
  u16* Wob = Wvb + NW;
  u16* Qb  = Wob + NW;       // Qb, Kb, VTb contiguous (gemm MODE 0 writes tz*NX offsets)
  u16* Kb  = Qb + NX;
  u16* VTb = Kb + NX;        // V written pre-transposed [B,H,D,S] by the epilogue
  u16* Ab  = VTb + NX;

  cast_bf16<<<(int)(NX / 4 / 256), 256, 0, stream>>>((const float4*)x, (ushort4*)xb, (int)(NX / 4));
  cast4_bf16<<<dim3((int)(NW / 4 / 256), 4), 256, 0, stream>>>(
      (const float4*)Wq, (const float4*)Wk, (const float4*)Wv, (const float4*)Wo,
      (ushort4*)Wqb, (ushort4*)Wkb, (ushort4*)Wvb, (ushort4*)Wob, (int)(NW / 4));

  // fused QKV projection + rope(Q,K) + V-transpose, all in one dispatch
  gemm256<0><<<dim3(768), 512, 0, stream>>>(xb, Wqb, Qb, M_, 3 * E_, E_, 3, cosT, sinT);

  attn_fwd<<<dim3(512), 512, 0, stream>>>(Qb, Kb, VTb, Ab);

  gemm256<1><<<dim3(256), 512, 0, stream>>>(Ab, Wob, out, M_, E_, E_, 1, nullptr, nullptr);
}

// Round 14
// 298.561 us; speedup vs baseline: 1.2107x; 1.1316x over previous
//
#include <hip/hip_runtime.h>
#include <stdint.h>

typedef unsigned short u16;
typedef __attribute__((ext_vector_type(8))) short short8;
typedef __attribute__((ext_vector_type(4))) float f32x4;
typedef __attribute__((ext_vector_type(16))) float f32x16;

#define B_ 2
#define S_ 2048
#define E_ 2048
#define H_ 16
#define D_ 128
#define M_ 4096

__device__ __forceinline__ u16 f2bf(float f) {
  unsigned u = __float_as_uint(f);
  u = u + 0x7FFFu + ((u >> 16) & 1u);
  return (u16)(u >> 16);
}
__device__ __forceinline__ float bf2f(u16 h) {
  return __uint_as_float(((unsigned)h) << 16);
}

// async global->LDS, 16B per lane; LDS dest is wave-uniform base + lane*16
#define GLD16(gp, lp) __builtin_amdgcn_global_load_lds(                      \
    (__attribute__((address_space(1))) void*)(gp),                           \
    (__attribute__((address_space(3))) void*)(lp), 16, 0, 0)

// ---------------------------------------------------------------- cast f32->bf16
__global__ void cast_bf16(const float4* __restrict__ src, ushort4* __restrict__ dst, int n4) {
  int i = blockIdx.x * 256 + threadIdx.x;
  if (i < n4) {
    float4 v = src[i];
    ushort4 o;
    o.x = f2bf(v.x); o.y = f2bf(v.y); o.z = f2bf(v.z); o.w = f2bf(v.w);
    dst[i] = o;
  }
}

// 4 weight casts in one launch (blockIdx.y selects the tensor); o0..o2 contiguous -> [Wq;Wk;Wv]
__global__ void cast4_bf16(const float4* __restrict__ w0, const float4* __restrict__ w1,
                           const float4* __restrict__ w2, const float4* __restrict__ w3,
                           ushort4* __restrict__ o0, ushort4* __restrict__ o1,
                           ushort4* __restrict__ o2, ushort4* __restrict__ o3, int n4) {
  const int i = blockIdx.x * 256 + threadIdx.x;
  if (i >= n4) return;
  const float4* s; ushort4* d;
  switch (blockIdx.y) {
    case 0: s = w0; d = o0; break;
    case 1: s = w1; d = o1; break;
    case 2: s = w2; d = o2; break;
    default: s = w3; d = o3; break;
  }
  float4 v = s[i];
  ushort4 o;
  o.x = f2bf(v.x); o.y = f2bf(v.y); o.z = f2bf(v.z); o.w = f2bf(v.w);
  d[i] = o;
}

// ---------------------------------------------------------------- GEMM v4 (proven 123 us): phased,
// 2 barriers/tile, fused RoPE + V-transpose epilogue (MODE 0).  Unchanged from round 10.
template <int MODE>
__launch_bounds__(512, 1)
__global__ void gemm256(const u16* __restrict__ A, const u16* __restrict__ Bw,
                        void* __restrict__ Cp, int M, int N, int K, int bxpx,
                        const float* __restrict__ cosT, const float* __restrict__ sinT) {
  __shared__ alignas(16) u16 SMEM[73728];   // 144 KB: LA 3x8192 u16 | LB 3x16384 u16
  u16* const LA = SMEM;
  u16* const LB = SMEM + 24576;
  const int tid = threadIdx.x, wave = tid >> 6, lane = tid & 63;
  const int xcd = blockIdx.x & 7;
  const int j = blockIdx.x >> 3;
  const int bx = xcd * bxpx + (j % bxpx);
  const int by = j / bxpx;
  const int m0 = by * 128, n0 = bx * 256;
  const int wm = (wave >> 2) * 64, wn = (wave & 3) * 64;
  const int lrow = lane & 15, lq = lane >> 4;

  auto stage0 = [&](int buf, int kt) {   // A tile (2 issues) + B issue 0
    const int k0 = kt * 64;
#pragma unroll
    for (int i = 0; i < 2; ++i) {
      const int c = i * 512 + tid;
      const int row = c >> 3, k = c & 7;
      GLD16(A + (size_t)(m0 + row) * K + k0 + ((k ^ (row & 7)) * 8),
            LA + buf * 8192 + i * 4096 + wave * 512);
    }
    {
      const int c = tid;
      const int row = c >> 3, k = c & 7;
      GLD16(Bw + (size_t)(n0 + row) * K + k0 + ((k ^ (row & 7)) * 8),
            LB + buf * 16384 + wave * 512);
    }
  };
  auto stage1 = [&](int buf, int kt) {   // B issues 1..3
    const int k0 = kt * 64;
#pragma unroll
    for (int i = 1; i < 4; ++i) {
      const int c = i * 512 + tid;
      const int row = c >> 3, k = c & 7;
      GLD16(Bw + (size_t)(n0 + row) * K + k0 + ((k ^ (row & 7)) * 8),
            LB + buf * 16384 + i * 4096 + wave * 512);
    }
  };

  f32x4 acc[4][4] = {};
  const int NT = K >> 6;                 // 32
  stage0(0, 0); stage1(0, 0);
  stage0(1, 1); stage1(1, 1);
  asm volatile("s_waitcnt vmcnt(6) lgkmcnt(0)" ::: "memory");  // tile 0 staged
  __builtin_amdgcn_sched_barrier(0);
  __builtin_amdgcn_s_barrier();

  for (int t = 0; t < NT; ++t) {
    const int cur = t % 3;
    const int sb = (t + 2) % 3;
    const bool dostage = (t + 2) < NT;

    // ===== phase A (k-chunk 0) =====
    short8 a0[4], b0[4];
#pragma unroll
    for (int m = 0; m < 4; ++m) {
      const int row = wm + m * 16 + lrow;
      a0[m] = *(const short8*)&LA[cur * 8192 + row * 64 + ((lq ^ (row & 7)) * 8)];
    }
#pragma unroll
    for (int n = 0; n < 4; ++n) {
      const int row = wn + n * 16 + lrow;
      b0[n] = *(const short8*)&LB[cur * 16384 + row * 64 + ((lq ^ (row & 7)) * 8)];
    }
    if (dostage) stage0(sb, t + 2);
    __builtin_amdgcn_sched_barrier(0);
    __builtin_amdgcn_s_barrier();
    __builtin_amdgcn_sched_barrier(0);
    __builtin_amdgcn_s_setprio(1);
#pragma unroll
    for (int m = 0; m < 4; ++m)
#pragma unroll
      for (int n = 0; n < 4; ++n)
        acc[m][n] = __builtin_amdgcn_mfma_f32_16x16x32_bf16(a0[m], b0[n], acc[m][n], 0, 0, 0);
    __builtin_amdgcn_s_setprio(0);

    // ===== phase B (k-chunk 1) =====
    short8 a1[4], b1[4];
#pragma unroll
    for (int m = 0; m < 4; ++m) {
      const int row = wm + m * 16 + lrow;
      a1[m] = *(const short8*)&LA[cur * 8192 + row * 64 + (((4 + lq) ^ (row & 7)) * 8)];
    }
#pragma unroll
    for (int n = 0; n < 4; ++n) {
      const int row = wn + n * 16 + lrow;
      b1[n] = *(const short8*)&LB[cur * 16384 + row * 64 + (((4 + lq) ^ (row & 7)) * 8)];
    }
    if (dostage) stage1(sb, t + 2);
    if (t < NT - 2) { asm volatile("s_waitcnt vmcnt(6) lgkmcnt(0)" ::: "memory"); }
    else            { asm volatile("s_waitcnt vmcnt(0) lgkmcnt(0)" ::: "memory"); }
    __builtin_amdgcn_sched_barrier(0);
    __builtin_amdgcn_s_barrier();
    __builtin_amdgcn_sched_barrier(0);
    __builtin_amdgcn_s_setprio(1);
#pragma unroll
    for (int m = 0; m < 4; ++m)
#pragma unroll
      for (int n = 0; n < 4; ++n)
        acc[m][n] = __builtin_amdgcn_mfma_f32_16x16x32_bf16(a1[m], b1[n], acc[m][n], 0, 0, 0);
    __builtin_amdgcn_s_setprio(0);
  }

  const int rbase = lq * 4;  // C/D: col = lane&15, row = (lane>>4)*4 + r
  if (MODE == 1) {
#pragma unroll
    for (int m = 0; m < 4; ++m)
#pragma unroll
      for (int n = 0; n < 4; ++n)
#pragma unroll
        for (int r = 0; r < 4; ++r) {
          const int mm = m0 + wm + m * 16 + rbase + r;
          const int nn = n0 + wn + n * 16 + lrow;
          ((float*)Cp)[(size_t)mm * N + nn] = acc[m][n][r];
        }
    return;
  }

  // ===== MODE 0 epilogue: C tile -> LDS -> fused rope / V-transpose =====
  u16* ct = SMEM;                        // [128][272] bf16
#pragma unroll
  for (int m = 0; m < 4; ++m)
#pragma unroll
    for (int n = 0; n < 4; ++n)
#pragma unroll
      for (int r = 0; r < 4; ++r)
        ct[(wm + m * 16 + rbase + r) * 272 + wn + n * 16 + lrow] = f2bf(acc[m][n][r]);
  __syncthreads();

  const int tz = n0 >> 11;               // 0=Q 1=K 2=V (block-uniform)
  const int bb = m0 >> 11, s0 = m0 & (S_ - 1);
  const int h0 = (n0 >> 7) & 15;
  const size_t NXc = (size_t)B_ * S_ * E_;
  u16* dst = (u16*)Cp + (size_t)tz * NXc;

  if (tz < 2) {
    const float sc = (tz == 0) ? 0.12751744154f : 1.f;  // Q pre-scale (1/sqrt(D))*log2(e)
#pragma unroll
    for (int i = 0; i < 8; ++i) {
      const int idx = i * 512 + tid;           // 4096 tasks = 128 rows x 32 col-chunks
      const int row = idx >> 5, c8 = (idx & 31) * 8;
      const int head = c8 >> 7, hd = c8 & 127;
      const int s = s0 + row;
      short8 self = *(const short8*)&ct[row * 272 + c8];
      short8 part = *(const short8*)&ct[row * 272 + (c8 ^ 64)];
      float4 cv0 = *(const float4*)&cosT[s * D_ + hd];
      float4 cv1 = *(const float4*)&cosT[s * D_ + hd + 4];
      float4 sv0 = *(const float4*)&sinT[s * D_ + hd];
      float4 sv1 = *(const float4*)&sinT[s * D_ + hd + 4];
      float cv[8] = {cv0.x, cv0.y, cv0.z, cv0.w, cv1.x, cv1.y, cv1.z, cv1.w};
      float sv[8] = {sv0.x, sv0.y, sv0.z, sv0.w, sv1.x, sv1.y, sv1.z, sv1.w};
      short8 o;
      if (hd < 64) {
#pragma unroll
        for (int jj = 0; jj < 8; ++jj) {
          const float x1 = bf2f((u16)self[jj]), x2 = bf2f((u16)part[jj]);
          o[jj] = (short)f2bf((x1 * cv[jj] - x2 * sv[jj]) * sc);
        }
      } else {
#pragma unroll
        for (int jj = 0; jj < 8; ++jj) {
          const float x2 = bf2f((u16)self[jj]), x1 = bf2f((u16)part[jj]);
          o[jj] = (short)f2bf((x2 * cv[jj] + x1 * sv[jj]) * sc);
        }
      }
      *(short8*)&dst[(((size_t)bb * H_ + h0 + head) * S_ + s) * D_ + hd] = o;
    }
  } else {
#pragma unroll
    for (int i = 0; i < 8; ++i) {
      const int task = i * 512 + tid;          // 4096 = 256 d-cols x 16 s-chunks
      const int dcol = task & 255, sch = task >> 8;
      short8 v;
#pragma unroll
      for (int jj = 0; jj < 8; ++jj) v[jj] = ct[(sch * 8 + jj) * 272 + dcol];
      const int h = h0 + (dcol >> 7), hd = dcol & 127;
      *(short8*)&dst[(((size_t)bb * H_ + h) * D_ + hd) * S_ + s0 + sch * 8] = v;
    }
  }
}

// ---------------------------------------------------------------- causal flash attention v9
// Round-13 structure with the launch-bounds fix. EMPIRICAL (r4/r12/r13): hipcc treats the
// 2nd __launch_bounds__ arg as BLOCKS-per-CU: (512,2) -> 16 waves/CU -> 128-VGPR cap (r4
// measured 124, no spill); (512,4)/(1024,*) -> 64-VGPR cap -> catastrophic spill.
// 512 blocks x 512 thr, 2 blocks/CU (LDS 66 KB). Block = one 128-row q-tile (4 q-waves x
// 32q), 2 KV-parity groups, KVBLK=32 double-buffered per group. iters = 2qt+2 (uniform
// in-block); cross-block balance via complementary-qt dispatch pairing (slot s <-> s+32).
__launch_bounds__(512, 2)
__global__ void attn_fwd(const u16* __restrict__ Q, const u16* __restrict__ Kt,
                         const u16* __restrict__ VT, u16* __restrict__ Out) {
  __shared__ alignas(16) u16 SB[2][2][8192];   // [grp][buf][ K 32x128 | V^T 128x32 ] = 64 KB
  __shared__ float MLB[4][64][2];
  const int tid = threadIdx.x, wave = tid >> 6, lane = tid & 63;
  const int grp = wave >> 2, w4 = wave & 3;
  // block mapping: xcd-major, complementary qt halves for co-resident balance
  const int hw = blockIdx.x;
  const int xcd = hw & 7, slot = hw >> 3;       // slot 0..63
  const int half = slot >> 5, s5 = slot & 31;
  const int bh = xcd * 4 + (s5 >> 4) + 2 * half;   // 4 heads per XCD (L2 locality)
  const int qt = half ? 15 - (s5 & 15) : (s5 & 15);
  const int bb = bh >> 4, h = bh & 15;
  const u16* Qh = Q + (size_t)bh * S_ * D_;
  const u16* Kh = Kt + (size_t)bh * S_ * D_;
  const u16* Vh = VT + (size_t)bh * D_ * S_;
  const int l31 = lane & 31, hi = lane >> 5;

  auto stage = [&](int buf, int kv0) {   // my group's 4 waves stage my stream (K 8KB + V 8KB)
#pragma unroll
    for (int pp = 0; pp < 2; ++pp) {
      const int g = pp * 4 + w4;       // 0..7 (wave-uniform)
      const int c = g * 64 + lane;     // 0..511
      const int srow = c >> 4, dch = c & 15;
      GLD16(Kh + (size_t)(kv0 + srow) * D_ + ((dch ^ (srow & 7)) * 8), &SB[grp][buf][g * 512]);
      const int drow = c >> 2, sch = c & 3;
      GLD16(Vh + (size_t)drow * S_ + kv0 + ((sch ^ (drow & 3)) * 8), &SB[grp][buf][4096 + g * 512]);
    }
  };

  float* obuf = (float*)&SB[0][0][0];    // merge region: all 64 KB of SB (16384 floats)

  const int iters = 2 * qt + 2;          // my group's KV32 tiles: tix = 2i + grp
  const int q0 = qt * 128 + w4 * 32;
  const int qg = q0 + l31;

  // Q fragments (B-operand): lane holds Q[qg][m*16 + hi*8 + j], j=0..7
  short8 qf[8];
#pragma unroll
  for (int m = 0; m < 8; ++m)
    qf[m] = *(const short8*)&Qh[(size_t)qg * D_ + m * 16 + hi * 8];

  f32x16 od[4] = {};   // out^T: od[dt], d = dt*32 + (reg&3)+8*(reg>>2)+4*hi, col q = l31
  float mr = 0.f, lsum = 0.f;            // mr init 0: masked tiles give exp2(-1e30) = 0

  stage(0, grp * 32);
  int cur = 0;

  for (int i = 0; i < iters; ++i) {
    __syncthreads();  // both streams' buf[cur] staged; prior reads of buf[cur^1] done
    if (i + 1 < iters) stage(cur ^ 1, (2 * (i + 1) + grp) * 32);
    const int kv0 = (2 * i + grp) * 32;
    const u16* Kc = &SB[grp][cur][0];
    const u16* Vc = &SB[grp][cur][4096];

    // QK^T swapped: S^T[k][q] for 32 kv rows
    f32x16 s0 = {};
    __builtin_amdgcn_s_setprio(1);
#pragma unroll
    for (int m = 0; m < 8; ++m) {
      const int col = m * 16 + hi * 8;
      short8 k0 = *(const short8*)&Kc[l31 * 128 + (col ^ ((l31 & 7) << 3))];
      s0 = __builtin_amdgcn_mfma_f32_32x32x16_bf16(k0, qf[m], s0, 0, 0, 0);
    }
    __builtin_amdgcn_s_setprio(0);

    // causal mask
    if (kv0 + 31 > q0) {
#pragma unroll
      for (int r = 0; r < 16; ++r) {
        const int kg = kv0 + (r & 3) + 8 * (r >> 2) + 4 * hi;
        if (kg > qg) s0[r] = -1e30f;
      }
    }

    // online softmax (scores in log2 units via pre-scaled Q)
    float m0 = fmaxf(s0[0], s0[1]), m1 = fmaxf(s0[2], s0[3]);
    float m2 = fmaxf(s0[4], s0[5]), m3 = fmaxf(s0[6], s0[7]);
    float m4 = fmaxf(s0[8], s0[9]), m5 = fmaxf(s0[10], s0[11]);
    float m6 = fmaxf(s0[12], s0[13]), m7 = fmaxf(s0[14], s0[15]);
    float mloc = fmaxf(fmaxf(fmaxf(m0, m1), fmaxf(m2, m3)),
                       fmaxf(fmaxf(m4, m5), fmaxf(m6, m7)));
    const float mx = fmaxf(mloc, __shfl_xor(mloc, 32));
    const bool need = !__all(mx <= mr + 8.f);   // defer-max (T13)
    float corr = 1.f;
    if (need) {
      const float mnew = fmaxf(mr, mx);
      corr = exp2f(mr - mnew);
      mr = mnew;
    }
    float sloc = 0.f;
#pragma unroll
    for (int r = 0; r < 16; ++r) { s0[r] = exp2f(s0[r] - mr); sloc += s0[r]; }
    const float rsum = sloc + __shfl_xor(sloc, 32);
    lsum = lsum * corr + rsum;
    if (need) {
#pragma unroll
      for (int dt = 0; dt < 4; ++dt)
#pragma unroll
        for (int r = 0; r < 16; ++r) od[dt][r] *= corr;
    }

    // pack P to bf16 words: W0[c][pr] covers k32 = 8c + 4hi + {2pr, 2pr+1}
    unsigned W0[4][2];
#pragma unroll
    for (int c = 0; c < 4; ++c)
#pragma unroll
      for (int pr = 0; pr < 2; ++pr)
        asm("v_cvt_pk_bf16_f32 %0, %1, %2"
            : "=v"(W0[c][pr]) : "v"(s0[4 * c + 2 * pr]), "v"(s0[4 * c + 2 * pr + 1]));

    // PV: out^T += V^T * P^T ; B-frag for group kk needs k = kk*16 + hi*8 + j
    __builtin_amdgcn_s_setprio(1);
#pragma unroll
    for (int kk = 0; kk < 2; ++kk) {
      const int cown = 2 * kk + hi, csend = 2 * kk + 1 - hi;
      const unsigned o0 = W0[cown][0], o1 = W0[cown][1];
      const unsigned r0 = (unsigned)__shfl_xor((int)W0[csend][0], 32);
      const unsigned r1 = (unsigned)__shfl_xor((int)W0[csend][1], 32);
      uint4 bw;
      if (hi == 0) bw = make_uint4(o0, o1, r0, r1);
      else         bw = make_uint4(r0, r1, o0, o1);
      const short8 pf = *(const short8*)&bw;
      const int slotv = 2 * kk + hi;     // V chunk col for this k-16 group
#pragma unroll
      for (int dt = 0; dt < 4; ++dt) {
        const int row = dt * 32 + l31;
        const short8 vf = *(const short8*)&Vc[row * 32 + ((slotv ^ (row & 3)) * 8)];
        od[dt] = __builtin_amdgcn_mfma_f32_32x32x16_bf16(vf, pf, od[dt], 0, 0, 0);
      }
    }
    __builtin_amdgcn_s_setprio(0);
    cur ^= 1;
  }

  // ---- merge the two parity partials (group B -> LDS -> group A combines) ----
  __syncthreads();                     // all computes done; SB reusable as O-buffer
  if (grp == 1) {
    MLB[w4][lane][0] = mr;
    MLB[w4][lane][1] = lsum;
#pragma unroll
    for (int dt = 0; dt < 4; ++dt)
#pragma unroll
      for (int r = 0; r < 16; ++r)
        obuf[(dt * 16 + r) * 256 + w4 * 64 + lane] = od[dt][r];  // lane-major: conflict-free
  }
  __syncthreads();
  if (grp == 0) {
    const float mB = MLB[w4][lane][0];
    const float lB = MLB[w4][lane][1];
    const float m = fmaxf(mr, mB);
    const float aA = exp2f(mr - m), aB = exp2f(mB - m);
    lsum = lsum * aA + lB * aB;
#pragma unroll
    for (int dt = 0; dt < 4; ++dt)
#pragma unroll
      for (int r = 0; r < 16; ++r)
        od[dt][r] = od[dt][r] * aA + obuf[(dt * 16 + r) * 256 + w4 * 64 + lane] * aB;

    // finalize: o /= l, write bf16 to attn buffer laid out [B,S,E]
    const float inv = 1.f / lsum;
    const size_t obase = ((size_t)bb * S_ + qg) * E_ + h * D_;
#pragma unroll
    for (int dt = 0; dt < 4; ++dt)
#pragma unroll
      for (int g = 0; g < 4; ++g) {
        ushort4 w;
        w.x = f2bf(od[dt][4 * g + 0] * inv);
        w.y = f2bf(od[dt][4 * g + 1] * inv);
        w.z = f2bf(od[dt][4 * g + 2] * inv);
        w.w = f2bf(od[dt][4 * g + 3] * inv);
        *(ushort4*)&Out[obase + dt * 32 + 8 * g + 4 * hi] = w;
      }
  }
}

// ---------------------------------------------------------------- launcher
extern "C" void kernel_launch(void* const* d_in, const int* in_sizes, int n_in,
                              void* d_out, int out_size, void* d_ws, size_t ws_size,
                              hipStream_t stream) {
  const float* x    = (const float*)d_in[0];
  const float* cosT = (const float*)d_in[1];
  const float* sinT = (const float*)d_in[2];
  const float* Wq   = (const float*)d_in[3];
  const float* Wk   = (const float*)d_in[4];
  const float* Wv   = (const float*)d_in[5];
  const float* Wo   = (const float*)d_in[6];
  float* out = (float*)d_out;

  const size_t NX = (size_t)B_ * S_ * E_;  // 8388608
  const size_t NW = (size_t)E_ * E_;       // 4194304
  u16* ws  = (u16*)d_ws;
  u16* xb  = ws;
  u16* Wqb = xb + NX;        // [Wq;Wk;Wv] contiguous -> fused [6144][2048]
  u16* Wkb = Wqb + NW;
  u16* Wvb = Wkb + NW;
  u16* Wob = Wvb + NW;
  u16* Qb  = Wob + NW;       // Qb, Kb, VTb contiguous (gemm MODE 0 writes tz*NX offsets)
  u16* Kb  = Qb + NX;
  u16* VTb = Kb + NX;        // V written pre-transposed [B,H,D,S] by the epilogue
  u16* Ab  = VTb + NX;

  cast_bf16<<<(int)(NX / 4 / 256), 256, 0, stream>>>((const float4*)x, (ushort4*)xb, (int)(NX / 4));
  cast4_bf16<<<dim3((int)(NW / 4 / 256), 4), 256, 0, stream>>>(
      (const float4*)Wq, (const float4*)Wk, (const float4*)Wv, (const float4*)Wo,
      (ushort4*)Wqb, (ushort4*)Wkb, (ushort4*)Wvb, (ushort4*)Wob, (int)(NW / 4));

  // fused QKV projection + rope(Q,K) + V-transpose, all in one dispatch
  gemm256<0><<<dim3(768), 512, 0, stream>>>(xb, Wqb, Qb, M_, 3 * E_, E_, 3, cosT, sinT);

  attn_fwd<<<dim3(512), 512, 0, stream>>>(Qb, Kb, VTb, Ab);

  gemm256<1><<<dim3(256), 512, 0, stream>>>(Ab, Wob, out, M_, E_, E_, 1, nullptr, nullptr);
}

// Round 15
// 249.111 us; speedup vs baseline: 1.4510x; 1.1985x over previous
//
#include <hip/hip_runtime.h>
#include <stdint.h>

typedef unsigned short u16;
typedef __attribute__((ext_vector_type(8))) short short8;
typedef __attribute__((ext_vector_type(4))) float f32x4;
typedef __attribute__((ext_vector_type(16))) float f32x16;

#define B_ 2
#define S_ 2048
#define E_ 2048
#define H_ 16
#define D_ 128
#define M_ 4096

__device__ __forceinline__ u16 f2bf(float f) {
  unsigned u = __float_as_uint(f);
  u = u + 0x7FFFu + ((u >> 16) & 1u);
  return (u16)(u >> 16);
}
__device__ __forceinline__ float bf2f(u16 h) {
  return __uint_as_float(((unsigned)h) << 16);
}

// async global->LDS, 16B per lane; LDS dest is wave-uniform base + lane*16
#define GLD16(gp, lp) __builtin_amdgcn_global_load_lds(                      \
    (__attribute__((address_space(1))) void*)(gp),                           \
    (__attribute__((address_space(3))) void*)(lp), 16, 0, 0)

// ---------------------------------------------------------------- cast f32->bf16
__global__ void cast_bf16(const float4* __restrict__ src, ushort4* __restrict__ dst, int n4) {
  int i = blockIdx.x * 256 + threadIdx.x;
  if (i < n4) {
    float4 v = src[i];
    ushort4 o;
    o.x = f2bf(v.x); o.y = f2bf(v.y); o.z = f2bf(v.z); o.w = f2bf(v.w);
    dst[i] = o;
  }
}

// 4 weight casts in one launch (blockIdx.y selects the tensor); o0..o2 contiguous -> [Wq;Wk;Wv]
__global__ void cast4_bf16(const float4* __restrict__ w0, const float4* __restrict__ w1,
                           const float4* __restrict__ w2, const float4* __restrict__ w3,
                           ushort4* __restrict__ o0, ushort4* __restrict__ o1,
                           ushort4* __restrict__ o2, ushort4* __restrict__ o3, int n4) {
  const int i = blockIdx.x * 256 + threadIdx.x;
  if (i >= n4) return;
  const float4* s; ushort4* d;
  switch (blockIdx.y) {
    case 0: s = w0; d = o0; break;
    case 1: s = w1; d = o1; break;
    case 2: s = w2; d = o2; break;
    default: s = w3; d = o3; break;
  }
  float4 v = s[i];
  ushort4 o;
  o.x = f2bf(v.x); o.y = f2bf(v.y); o.z = f2bf(v.z); o.w = f2bf(v.w);
  d[i] = o;
}

// ---------------------------------------------------------------- GEMM v4 (proven 123 us): phased,
// 2 barriers/tile, fused RoPE + V-transpose epilogue (MODE 0).  Round-10 configuration.
template <int MODE>
__launch_bounds__(512, 1)
__global__ void gemm256(const u16* __restrict__ A, const u16* __restrict__ Bw,
                        void* __restrict__ Cp, int M, int N, int K, int bxpx,
                        const float* __restrict__ cosT, const float* __restrict__ sinT) {
  __shared__ alignas(16) u16 SMEM[73728];   // 144 KB: LA 3x8192 u16 | LB 3x16384 u16
  u16* const LA = SMEM;
  u16* const LB = SMEM + 24576;
  const int tid = threadIdx.x, wave = tid >> 6, lane = tid & 63;
  const int xcd = blockIdx.x & 7;
  const int j = blockIdx.x >> 3;
  const int bx = xcd * bxpx + (j % bxpx);
  const int by = j / bxpx;
  const int m0 = by * 128, n0 = bx * 256;
  const int wm = (wave >> 2) * 64, wn = (wave & 3) * 64;
  const int lrow = lane & 15, lq = lane >> 4;

  auto stage0 = [&](int buf, int kt) {   // A tile (2 issues) + B issue 0
    const int k0 = kt * 64;
#pragma unroll
    for (int i = 0; i < 2; ++i) {
      const int c = i * 512 + tid;
      const int row = c >> 3, k = c & 7;
      GLD16(A + (size_t)(m0 + row) * K + k0 + ((k ^ (row & 7)) * 8),
            LA + buf * 8192 + i * 4096 + wave * 512);
    }
    {
      const int c = tid;
      const int row = c >> 3, k = c & 7;
      GLD16(Bw + (size_t)(n0 + row) * K + k0 + ((k ^ (row & 7)) * 8),
            LB + buf * 16384 + wave * 512);
    }
  };
  auto stage1 = [&](int buf, int kt) {   // B issues 1..3
    const int k0 = kt * 64;
#pragma unroll
    for (int i = 1; i < 4; ++i) {
      const int c = i * 512 + tid;
      const int row = c >> 3, k = c & 7;
      GLD16(Bw + (size_t)(n0 + row) * K + k0 + ((k ^ (row & 7)) * 8),
            LB + buf * 16384 + i * 4096 + wave * 512);
    }
  };

  f32x4 acc[4][4] = {};
  const int NT = K >> 6;                 // 32
  stage0(0, 0); stage1(0, 0);
  stage0(1, 1); stage1(1, 1);
  asm volatile("s_waitcnt vmcnt(6) lgkmcnt(0)" ::: "memory");  // tile 0 staged
  __builtin_amdgcn_sched_barrier(0);
  __builtin_amdgcn_s_barrier();

  for (int t = 0; t < NT; ++t) {
    const int cur = t % 3;
    const int sb = (t + 2) % 3;
    const bool dostage = (t + 2) < NT;

    // ===== phase A (k-chunk 0) =====
    short8 a0[4], b0[4];
#pragma unroll
    for (int m = 0; m < 4; ++m) {
      const int row = wm + m * 16 + lrow;
      a0[m] = *(const short8*)&LA[cur * 8192 + row * 64 + ((lq ^ (row & 7)) * 8)];
    }
#pragma unroll
    for (int n = 0; n < 4; ++n) {
      const int row = wn + n * 16 + lrow;
      b0[n] = *(const short8*)&LB[cur * 16384 + row * 64 + ((lq ^ (row & 7)) * 8)];
    }
    if (dostage) stage0(sb, t + 2);
    __builtin_amdgcn_sched_barrier(0);
    __builtin_amdgcn_s_barrier();
    __builtin_amdgcn_sched_barrier(0);
    __builtin_amdgcn_s_setprio(1);
#pragma unroll
    for (int m = 0; m < 4; ++m)
#pragma unroll
      for (int n = 0; n < 4; ++n)
        acc[m][n] = __builtin_amdgcn_mfma_f32_16x16x32_bf16(a0[m], b0[n], acc[m][n], 0, 0, 0);
    __builtin_amdgcn_s_setprio(0);

    // ===== phase B (k-chunk 1) =====
    short8 a1[4], b1[4];
#pragma unroll
    for (int m = 0; m < 4; ++m) {
      const int row = wm + m * 16 + lrow;
      a1[m] = *(const short8*)&LA[cur * 8192 + row * 64 + (((4 + lq) ^ (row & 7)) * 8)];
    }
#pragma unroll
    for (int n = 0; n < 4; ++n) {
      const int row = wn + n * 16 + lrow;
      b1[n] = *(const short8*)&LB[cur * 16384 + row * 64 + (((4 + lq) ^ (row & 7)) * 8)];
    }
    if (dostage) stage1(sb, t + 2);
    if (t < NT - 2) { asm volatile("s_waitcnt vmcnt(6) lgkmcnt(0)" ::: "memory"); }
    else            { asm volatile("s_waitcnt vmcnt(0) lgkmcnt(0)" ::: "memory"); }
    __builtin_amdgcn_sched_barrier(0);
    __builtin_amdgcn_s_barrier();
    __builtin_amdgcn_sched_barrier(0);
    __builtin_amdgcn_s_setprio(1);
#pragma unroll
    for (int m = 0; m < 4; ++m)
#pragma unroll
      for (int n = 0; n < 4; ++n)
        acc[m][n] = __builtin_amdgcn_mfma_f32_16x16x32_bf16(a1[m], b1[n], acc[m][n], 0, 0, 0);
    __builtin_amdgcn_s_setprio(0);
  }

  const int rbase = lq * 4;  // C/D: col = lane&15, row = (lane>>4)*4 + r
  if (MODE == 1) {
#pragma unroll
    for (int m = 0; m < 4; ++m)
#pragma unroll
      for (int n = 0; n < 4; ++n)
#pragma unroll
        for (int r = 0; r < 4; ++r) {
          const int mm = m0 + wm + m * 16 + rbase + r;
          const int nn = n0 + wn + n * 16 + lrow;
          ((float*)Cp)[(size_t)mm * N + nn] = acc[m][n][r];
        }
    return;
  }

  // ===== MODE 0 epilogue: C tile -> LDS -> fused rope / V-transpose =====
  u16* ct = SMEM;                        // [128][272] bf16
#pragma unroll
  for (int m = 0; m < 4; ++m)
#pragma unroll
    for (int n = 0; n < 4; ++n)
#pragma unroll
      for (int r = 0; r < 4; ++r)
        ct[(wm + m * 16 + rbase + r) * 272 + wn + n * 16 + lrow] = f2bf(acc[m][n][r]);
  __syncthreads();

  const int tz = n0 >> 11;               // 0=Q 1=K 2=V (block-uniform)
  const int bb = m0 >> 11, s0 = m0 & (S_ - 1);
  const int h0 = (n0 >> 7) & 15;
  const size_t NXc = (size_t)B_ * S_ * E_;
  u16* dst = (u16*)Cp + (size_t)tz * NXc;

  if (tz < 2) {
    const float sc = (tz == 0) ? 0.12751744154f : 1.f;  // Q pre-scale (1/sqrt(D))*log2(e)
#pragma unroll
    for (int i = 0; i < 8; ++i) {
      const int idx = i * 512 + tid;           // 4096 tasks = 128 rows x 32 col-chunks
      const int row = idx >> 5, c8 = (idx & 31) * 8;
      const int head = c8 >> 7, hd = c8 & 127;
      const int s = s0 + row;
      short8 self = *(const short8*)&ct[row * 272 + c8];
      short8 part = *(const short8*)&ct[row * 272 + (c8 ^ 64)];
      float4 cv0 = *(const float4*)&cosT[s * D_ + hd];
      float4 cv1 = *(const float4*)&cosT[s * D_ + hd + 4];
      float4 sv0 = *(const float4*)&sinT[s * D_ + hd];
      float4 sv1 = *(const float4*)&sinT[s * D_ + hd + 4];
      float cv[8] = {cv0.x, cv0.y, cv0.z, cv0.w, cv1.x, cv1.y, cv1.z, cv1.w};
      float sv[8] = {sv0.x, sv0.y, sv0.z, sv0.w, sv1.x, sv1.y, sv1.z, sv1.w};
      short8 o;
      if (hd < 64) {
#pragma unroll
        for (int jj = 0; jj < 8; ++jj) {
          const float x1 = bf2f((u16)self[jj]), x2 = bf2f((u16)part[jj]);
          o[jj] = (short)f2bf((x1 * cv[jj] - x2 * sv[jj]) * sc);
        }
      } else {
#pragma unroll
        for (int jj = 0; jj < 8; ++jj) {
          const float x2 = bf2f((u16)self[jj]), x1 = bf2f((u16)part[jj]);
          o[jj] = (short)f2bf((x2 * cv[jj] + x1 * sv[jj]) * sc);
        }
      }
      *(short8*)&dst[(((size_t)bb * H_ + h0 + head) * S_ + s) * D_ + hd] = o;
    }
  } else {
#pragma unroll
    for (int i = 0; i < 8; ++i) {
      const int task = i * 512 + tid;          // 4096 = 256 d-cols x 16 s-chunks
      const int dcol = task & 255, sch = task >> 8;
      short8 v;
#pragma unroll
      for (int jj = 0; jj < 8; ++jj) v[jj] = ct[(sch * 8 + jj) * 272 + dcol];
      const int h = h0 + (dcol >> 7), hd = dcol & 127;
      *(short8*)&dst[(((size_t)bb * H_ + h) * D_ + hd) * S_ + s0 + sch * 8] = v;
    }
  }
}

// ---------------------------------------------------------------- causal flash attention v4 (proven: 82 us)
// ROUND-15: restored round-10/round-4 configuration verbatim. Lessons from r5/r12/r13/r14:
// (a) 1024-thr blocks and any occupancy-floor >= (512,2)-equivalent cap VGPR at 64 -> spill
//     catastrophe; (b) causal balance must be guaranteed WITHIN the block (seg-pair loop),
//     not hoped for via dispatch-order pairing across blocks (r14: Occ 15%, tail-bound).
// 8 waves x 32q, KV-parity split: waves 0-3 even KV64 tiles, waves 4-7 odd, SAME 128 q-rows.
// Per-group double-buffered K/V LDS stream; seg-pair (15-p, p) -> uniform 17 iters/block.
// LDS 133 KB -> 1 block/CU regardless of launch bounds, so use (512,1): full VGPR budget
// at identical occupancy (was capped at 128, measured 124).
__launch_bounds__(512, 1)
__global__ void attn_fwd(const u16* __restrict__ Q, const u16* __restrict__ Kt,
                         const u16* __restrict__ VT, u16* __restrict__ Out) {
  // SB[stream][buf]: K tile [64][128] (8192 u16) then V^T tile [128][64] (8192 u16)
  __shared__ alignas(16) u16 SB[2][2][16384];
  __shared__ float MLB[4][64][2];
  const int tid = threadIdx.x, wave = tid >> 6, lane = tid & 63;
  // bijective XCD swizzle (256 % 8 == 0): 4 heads per XCD
  const int hw = blockIdx.x;
  const int lid = (hw & 7) * 32 + (hw >> 3);
  const int p = lid & 7, bh = lid >> 3;
  const int bb = bh >> 4, h = bh & 15;
  const u16* Qh = Q + (size_t)bh * S_ * D_;
  const u16* Kh = Kt + (size_t)bh * S_ * D_;
  const u16* Vh = VT + (size_t)bh * D_ * S_;
  const int grp = wave >> 2, w4 = wave & 3;
  const int l31 = lane & 31, hi = lane >> 5;

  auto stage = [&](int buf, int kv0) {   // 4 waves of my group stage my stream
#pragma unroll
    for (int pp = 0; pp < 4; ++pp) {
      const int g = pp * 4 + w4;       // 0..15 (wave-uniform)
      const int c = g * 64 + lane;     // 0..1023
      const int srow = c >> 4, dch = c & 15;
      GLD16(Kh + (size_t)(kv0 + srow) * D_ + ((dch ^ (srow & 7)) * 8), &SB[grp][buf][g * 512]);
      const int drow = c >> 3, sch = c & 7;
      GLD16(Vh + (size_t)drow * S_ + kv0 + ((sch ^ (drow & 7)) * 8), &SB[grp][buf][8192 + g * 512]);
    }
  };

  float* obuf = (float*)&SB[1][0][0];  // 64 KB merge region (stream 1, both buffers)

  const int qts[2] = {15 - p, p};
#pragma unroll 1
  for (int seg = 0; seg < 2; ++seg) {
    const int t = qts[seg];
    const int iters = t + 1;           // nt = 2t+2 KV64 tiles, split by parity
    const int q0 = t * 128 + w4 * 32;
    const int qg = q0 + l31;

    // Q fragments (B-operand): lane holds Q[qg][m*16 + hi*8 + j], j=0..7
    short8 qf[8];
#pragma unroll
    for (int m = 0; m < 8; ++m)
      qf[m] = *(const short8*)&Qh[(size_t)qg * D_ + m * 16 + hi * 8];

    f32x16 od[4] = {};   // out^T: od[dt], d = dt*32 + (reg&3)+8*(reg>>2)+4*hi, col q = l31
    float mr = 0.f, lsum = 0.f;        // mr init 0: masked tiles give exp2(-1e30) = 0

    stage(0, grp * 64);                // my first tile = tile grp
    int cur = 0;

    for (int i = 0; i < iters; ++i) {
      __syncthreads();  // both streams' buf[cur] staged; prior reads of buf[cur^1] done
      if (i + 1 < iters) stage(cur ^ 1, (2 * (i + 1) + grp) * 64);
      const int kv0 = (2 * i + grp) * 64;
      const u16* Kc = &SB[grp][cur][0];
      const u16* Vc = &SB[grp][cur][8192];

      // QK^T swapped: S^T[k][q], two 32-kv halves
      f32x16 s0 = {}, s1 = {};
      __builtin_amdgcn_s_setprio(1);
#pragma unroll
      for (int m = 0; m < 8; ++m) {
        const int col = m * 16 + hi * 8;
        const int sw = (l31 & 7) << 3;
        short8 k0 = *(const short8*)&Kc[l31 * 128 + (col ^ sw)];
        short8 k1 = *(const short8*)&Kc[(32 + l31) * 128 + (col ^ sw)];
        s0 = __builtin_amdgcn_mfma_f32_32x32x16_bf16(k0, qf[m], s0, 0, 0, 0);
        s1 = __builtin_amdgcn_mfma_f32_32x32x16_bf16(k1, qf[m], s1, 0, 0, 0);
      }
      __builtin_amdgcn_s_setprio(0);

      // causal mask (only tiles overlapping this wave's diagonal)
      if (kv0 + 63 > q0) {
#pragma unroll
        for (int r = 0; r < 16; ++r) {
          const int k0g = kv0 + (r & 3) + 8 * (r >> 2) + 4 * hi;
          if (k0g > qg)      s0[r] = -1e30f;
          if (k0g + 32 > qg) s1[r] = -1e30f;
        }
      }

      // online softmax (scores already in log2 units via pre-scaled Q)
      float mloc = s0[0];
#pragma unroll
      for (int r = 1; r < 16; ++r) mloc = fmaxf(mloc, s0[r]);
#pragma unroll
      for (int r = 0; r < 16; ++r) mloc = fmaxf(mloc, s1[r]);
      const float mx = fmaxf(mloc, __shfl_xor(mloc, 32));
      const bool need = !__all(mx <= mr + 8.f);   // defer-max (T13)
      float corr = 1.f;
      if (need) {
        const float mnew = fmaxf(mr, mx);
        corr = exp2f(mr - mnew);
        mr = mnew;
      }
      float sloc = 0.f;
#pragma unroll
      for (int r = 0; r < 16; ++r) { s0[r] = exp2f(s0[r] - mr); sloc += s0[r]; }
#pragma unroll
      for (int r = 0; r < 16; ++r) { s1[r] = exp2f(s1[r] - mr); sloc += s1[r]; }
      const float rsum = sloc + __shfl_xor(sloc, 32);
      lsum = lsum * corr + rsum;
      if (need) {
#pragma unroll
        for (int dt = 0; dt < 4; ++dt)
#pragma unroll
          for (int r = 0; r < 16; ++r) od[dt][r] *= corr;
      }

      // pack P to bf16 words: W[half][c][pr] covers k32 = 8c + 4hi + {2pr, 2pr+1}
      unsigned W0[4][2], W1[4][2];
#pragma unroll
      for (int c = 0; c < 4; ++c)
#pragma unroll
        for (int pr = 0; pr < 2; ++pr) {
          asm("v_cvt_pk_bf16_f32 %0, %1, %2"
              : "=v"(W0[c][pr]) : "v"(s0[4 * c + 2 * pr]), "v"(s0[4 * c + 2 * pr + 1]));
          asm("v_cvt_pk_bf16_f32 %0, %1, %2"
              : "=v"(W1[c][pr]) : "v"(s1[4 * c + 2 * pr]), "v"(s1[4 * c + 2 * pr + 1]));
        }

      // PV: out^T += V^T * P^T ; B-frag for group kk needs k = kk*16 + hi*8 + j
      __builtin_amdgcn_s_setprio(1);
#pragma unroll
      for (int kk = 0; kk < 4; ++kk) {
        const int cown = 2 * (kk & 1) + hi, csend = 2 * (kk & 1) + 1 - hi;
        unsigned o0, o1, sd0, sd1;
        if (kk < 2) { o0 = W0[cown][0]; o1 = W0[cown][1]; sd0 = W0[csend][0]; sd1 = W0[csend][1]; }
        else        { o0 = W1[cown][0]; o1 = W1[cown][1]; sd0 = W1[csend][0]; sd1 = W1[csend][1]; }
        const unsigned r0 = (unsigned)__shfl_xor((int)sd0, 32);
        const unsigned r1 = (unsigned)__shfl_xor((int)sd1, 32);
        uint4 bw;
        if (hi == 0) bw = make_uint4(o0, o1, r0, r1);
        else         bw = make_uint4(r0, r1, o0, o1);
        const short8 pf = *(const short8*)&bw;
        const int slot = 2 * kk + hi;
#pragma unroll
        for (int dt = 0; dt < 4; ++dt) {
          const int row = dt * 32 + l31;
          const short8 vf = *(const short8*)&Vc[row * 64 + ((slot ^ (row & 7)) * 8)];
          od[dt] = __builtin_amdgcn_mfma_f32_32x32x16_bf16(vf, pf, od[dt], 0, 0, 0);
        }
      }
      __builtin_amdgcn_s_setprio(0);
      cur ^= 1;
    }

    // ---- merge the two parity partials (group B -> LDS -> group A combines) ----
    __syncthreads();                     // all computes done; stream-1 LDS reusable
    if (grp == 1) {
      MLB[w4][lane][0] = mr;
      MLB[w4][lane][1] = lsum;
#pragma unroll
      for (int dt = 0; dt < 4; ++dt)
#pragma unroll
        for (int r = 0; r < 16; ++r)
          obuf[(dt * 16 + r) * 256 + w4 * 64 + lane] = od[dt][r];  // lane-major: conflict-free
    }
    __syncthreads();
    if (grp == 0) {
      const float mB = MLB[w4][lane][0];
      const float lB = MLB[w4][lane][1];
      const float m = fmaxf(mr, mB);
      const float aA = exp2f(mr - m), aB = exp2f(mB - m);
      lsum = lsum * aA + lB * aB;
#pragma unroll
      for (int dt = 0; dt < 4; ++dt)
#pragma unroll
        for (int r = 0; r < 16; ++r)
          od[dt][r] = od[dt][r] * aA + obuf[(dt * 16 + r) * 256 + w4 * 64 + lane] * aB;

      // finalize: o /= l, write bf16 to attn buffer laid out [B,S,E]
      const float inv = 1.f / lsum;
      const size_t obase = ((size_t)bb * S_ + qg) * E_ + h * D_;
#pragma unroll
      for (int dt = 0; dt < 4; ++dt)
#pragma unroll
        for (int g = 0; g < 4; ++g) {
          ushort4 w;
          w.x = f2bf(od[dt][4 * g + 0] * inv);
          w.y = f2bf(od[dt][4 * g + 1] * inv);
          w.z = f2bf(od[dt][4 * g + 2] * inv);
          w.w = f2bf(od[dt][4 * g + 3] * inv);
          *(ushort4*)&Out[obase + dt * 32 + 8 * g + 4 * hi] = w;
        }
    }
    __syncthreads();                     // merge reads done before next seg restages SB
  }
}

// ---------------------------------------------------------------- launcher
extern "C" void kernel_launch(void* const* d_in, const int* in_sizes, int n_in,
                              void* d_out, int out_size, void* d_ws, size_t ws_size,
                              hipStream_t stream) {
  const float* x    = (const float*)d_in[0];
  const float* cosT = (const float*)d_in[1];
  const float* sinT = (const float*)d_in[2];
  const float* Wq   = (const float*)d_in[3];
  const float* Wk   = (const float*)d_in[4];
  const float* Wv   = (const float*)d_in[5];
  const float* Wo   = (const float*)d_in[6];
  float* out = (float*)d_out;

  const size_t NX = (size_t)B_ * S_ * E_;  // 8388608
  const size_t NW = (size_t)E_ * E_;       // 4194304
  u16* ws  = (u16*)d_ws;
  u16* xb  = ws;
  u16* Wqb = xb + NX;        // [Wq;Wk;Wv] contiguous -> fused [6144][2048]
  u16* Wkb = Wqb + NW;
  u16* Wvb = Wkb + NW;
  u16* Wob = Wvb + NW;
  u16* Qb  = Wob + NW;       // Qb, Kb, VTb contiguous (gemm MODE 0 writes tz*NX offsets)
  u16* Kb  = Qb + NX;
  u16* VTb = Kb + NX;        // V written pre-transposed [B,H,D,S] by the epilogue
  u16* Ab  = VTb + NX;

  cast_bf16<<<(int)(NX / 4 / 256), 256, 0, stream>>>((const float4*)x, (ushort4*)xb, (int)(NX / 4));
  cast4_bf16<<<dim3((int)(NW / 4 / 256), 4), 256, 0, stream>>>(
      (const float4*)Wq, (const float4*)Wk, (const float4*)Wv, (const float4*)Wo,
      (ushort4*)Wqb, (ushort4*)Wkb, (ushort4*)Wvb, (ushort4*)Wob, (int)(NW / 4));

  // fused QKV projection + rope(Q,K) + V-transpose, all in one dispatch
  gemm256<0><<<dim3(768), 512, 0, stream>>>(xb, Wqb, Qb, M_, 3 * E_, E_, 3, cosT, sinT);

  attn_fwd<<<dim3(256), 512, 0, stream>>>(Qb, Kb, VTb, Ab);

  gemm256<1><<<dim3(256), 512, 0, stream>>>(Ab, Wob, out, M_, E_, E_, 1, nullptr, nullptr);
}